// Round 11
// baseline (826.456 us; speedup 1.0000x reference)
//
#include <hip/hip_runtime.h>
#include <cmath>

#define NN 20000
#define NE 200000
#define SCAN_BLOCKS 79   // ceil(NN/256)
#define EBLK 3125        // NE/64
#define GRID_E 768       // persistent edge grid: 3 blocks/CU

typedef __attribute__((ext_vector_type(8))) short bf16x8;
typedef __attribute__((ext_vector_type(4))) float f32x4;
typedef unsigned int uint;

__device__ __forceinline__ float4 ld4(const float* p){ return *(const float4*)p; }

// RNE float->bf16
__device__ __forceinline__ uint packbf(float a, float b) {
  uint ua = __float_as_uint(a);
  uint ub = __float_as_uint(b);
  ua = (ua + 0x7fffu + ((ua >> 16) & 1u)) >> 16;
  ub = (ub + 0x7fffu + ((ub >> 16) & 1u)) >> 16;
  return ua | (ub << 16);
}
__device__ __forceinline__ float4 up4(uint2 u) {
  return make_float4(__uint_as_float(u.x << 16), __uint_as_float(u.x & 0xffff0000u),
                     __uint_as_float(u.y << 16), __uint_as_float(u.y & 0xffff0000u));
}

// GEMM -> packed bf16, 16 ch/thread; K literal (full unroll); optional row permutation.
template<int K>
__global__ void gemm16_bf16(const float* __restrict__ A, const float* __restrict__ B,
                            const float* __restrict__ bias, uint2* __restrict__ O,
                            int M, const int* __restrict__ map) {
  int idx = blockIdx.x * 256 + threadIdx.x;
  if (idx >= M * 4) return;
  int m = idx >> 2, jq = idx & 3;
  const float* a = A + (long)m * K;
  const float* b = B + jq * 16;
  float c00=0,c01=0,c02=0,c03=0,c04=0,c05=0,c06=0,c07=0;
  float c08=0,c09=0,c10=0,c11=0,c12=0,c13=0,c14=0,c15=0;
  #pragma unroll
  for (int k = 0; k < K; k++) {
    float av = a[k];
    const float* br = b + (long)k * 64;
    float4 b0 = ld4(br), b1 = ld4(br + 4), b2 = ld4(br + 8), b3 = ld4(br + 12);
    c00 = fmaf(av, b0.x, c00); c01 = fmaf(av, b0.y, c01); c02 = fmaf(av, b0.z, c02); c03 = fmaf(av, b0.w, c03);
    c04 = fmaf(av, b1.x, c04); c05 = fmaf(av, b1.y, c05); c06 = fmaf(av, b1.z, c06); c07 = fmaf(av, b1.w, c07);
    c08 = fmaf(av, b2.x, c08); c09 = fmaf(av, b2.y, c09); c10 = fmaf(av, b2.z, c10); c11 = fmaf(av, b2.w, c11);
    c12 = fmaf(av, b3.x, c12); c13 = fmaf(av, b3.y, c13); c14 = fmaf(av, b3.z, c14); c15 = fmaf(av, b3.w, c15);
  }
  const float* bb = bias + jq * 16;
  float4 v0 = ld4(bb), v1 = ld4(bb + 4), v2 = ld4(bb + 8), v3 = ld4(bb + 12);
  int mo = map ? map[m] : m;
  uint2* op = O + (long)mo * 16 + jq * 4;
  op[0] = make_uint2(packbf(c00 + v0.x, c01 + v0.y), packbf(c02 + v0.z, c03 + v0.w));
  op[1] = make_uint2(packbf(c04 + v1.x, c05 + v1.y), packbf(c06 + v1.z, c07 + v1.w));
  op[2] = make_uint2(packbf(c08 + v2.x, c09 + v2.y), packbf(c10 + v2.z, c11 + v2.w));
  op[3] = make_uint2(packbf(c12 + v3.x, c13 + v3.y), packbf(c14 + v3.z, c15 + v3.w));
}

__global__ void zero_i32(int* __restrict__ p, int n) {
  int i = blockIdx.x * 256 + threadIdx.x;
  if (i < n) p[i] = 0;
}

__global__ void count_deg(const int* __restrict__ dst, int* __restrict__ deg) {
  int e = blockIdx.x * 256 + threadIdx.x;
  if (e < NE) atomicAdd(&deg[dst[e]], 1);
}

__global__ void scan1(const int* __restrict__ deg, int* __restrict__ off, int* __restrict__ bsum) {
  __shared__ int buf[256];
  int t = threadIdx.x;
  int g = blockIdx.x * 256 + t;
  int v = (g < NN) ? deg[g] : 0;
  buf[t] = v;
  __syncthreads();
  for (int s = 1; s < 256; s <<= 1) {
    int x = (t >= s) ? buf[t - s] : 0;
    __syncthreads();
    buf[t] += x;
    __syncthreads();
  }
  if (g < NN) off[g] = buf[t] - v;
  if (t == 255) bsum[blockIdx.x] = buf[255];
}

__global__ void scan2(int* __restrict__ bsum, int* __restrict__ off) {
  __shared__ int buf[128];
  int t = threadIdx.x;
  int v = (t < SCAN_BLOCKS) ? bsum[t] : 0;
  buf[t] = v;
  __syncthreads();
  for (int s = 1; s < 128; s <<= 1) {
    int x = (t >= s) ? buf[t - s] : 0;
    __syncthreads();
    buf[t] += x;
    __syncthreads();
  }
  if (t < SCAN_BLOCKS) bsum[t] = buf[t] - v;
  if (t == 127) off[NN] = buf[127];
}

__global__ void scan3(int* __restrict__ off, const int* __restrict__ bsum) {
  int g = blockIdx.x * 256 + threadIdx.x;
  if (g < NN) off[g] += bsum[blockIdx.x];
}

__global__ void fill_csr(const int* __restrict__ dst, const int* __restrict__ src,
                         const int* __restrict__ off, int* __restrict__ cursor,
                         int* __restrict__ esrc, int* __restrict__ edst,
                         int* __restrict__ csr_pos) {
  int e = blockIdx.x * 256 + threadIdx.x;
  if (e >= NE) return;
  int d = dst[e];
  int p = atomicAdd(&cursor[d], 1);
  int pos = off[d] + p;
  esrc[pos] = src[e];
  edst[pos] = d;
  csr_pos[e] = pos;
}

// Wcat[l][c][k] bf16 (k<192 = Wni|Wnj|Wfij cols), WcT[l][c<64][k<256] = Wnode[kk][h*64+c]/4,
// bmean[l][c<64] = mean_h bnode.
__global__ void prep_w(const float* __restrict__ Wni, const float* __restrict__ Wnj,
                       const float* __restrict__ Wfij, const float* __restrict__ Wnode,
                       const float* __restrict__ bnode,
                       uint* __restrict__ Wcat, uint* __restrict__ WcT,
                       float* __restrict__ bmean) {
  int rid = blockIdx.x * 256 + threadIdx.x;
  if (rid < 512) {
    int l = rid >> 8, c = rid & 255;
    uint* D = Wcat + (size_t)l * 24576 + c * 96;
    for (int k8 = 0; k8 < 24; k8++) {
      int ss = k8 >> 3;
      const float* S = (ss == 0 ? Wni : ss == 1 ? Wnj : Wfij) + l * 16384;
      int kl = (k8 & 7) * 8;
      uint u0 = packbf(S[(kl+0)*256 + c], S[(kl+1)*256 + c]);
      uint u1 = packbf(S[(kl+2)*256 + c], S[(kl+3)*256 + c]);
      uint u2 = packbf(S[(kl+4)*256 + c], S[(kl+5)*256 + c]);
      uint u3 = packbf(S[(kl+6)*256 + c], S[(kl+7)*256 + c]);
      *((uint4*)(D + k8 * 4)) = make_uint4(u0, u1, u2, u3);
    }
  } else if (rid < 640) {
    int idx = rid - 512;
    int l = idx >> 6, c = idx & 63;
    const float* S = Wnode + l * 16384;
    uint* D = WcT + (size_t)l * 8192 + c * 128;
    for (int kp = 0; kp < 128; kp++) {
      int k0 = kp * 2, k1 = kp * 2 + 1;
      float v0 = S[(k0 & 63) * 256 + (k0 >> 6) * 64 + c] * 0.25f;
      float v1 = S[(k1 & 63) * 256 + (k1 >> 6) * 64 + c] * 0.25f;
      D[kp] = packbf(v0, v1);
    }
  } else if (rid < 768) {
    int idx = rid - 640;
    int l = idx >> 6, c = idx & 63;
    const float* S = bnode + l * 256;
    bmean[l * 64 + c] = 0.25f * (S[c] + S[64 + c] + S[128 + c] + S[192 + c]);
  }
}

// compute one 32-edge chunk (two 16-edge B-subtiles) from staged LDS buffer bp
__device__ __forceinline__ void edge_compute(
    const uint* bp, const uint* __restrict__ Wcat_l,
    const float* __restrict__ be_l, const float* __restrict__ attn_l,
    int w, int col, int quad, int ch,
    float (&ma)[2][2][4], float (&red)[4][2][33][6])
{
  bf16x8 Ba[6], Bb[6];
  Ba[0] = *(const bf16x8*)&bp[col * 36 + quad * 4];
  Ba[1] = *(const bf16x8*)&bp[col * 36 + 16 + quad * 4];
  Ba[2] = *(const bf16x8*)&bp[(32 + col) * 36 + quad * 4];
  Ba[3] = *(const bf16x8*)&bp[(32 + col) * 36 + 16 + quad * 4];
  Ba[4] = *(const bf16x8*)&bp[(64 + col) * 36 + quad * 4];
  Ba[5] = *(const bf16x8*)&bp[(64 + col) * 36 + 16 + quad * 4];
  Bb[0] = *(const bf16x8*)&bp[(16 + col) * 36 + quad * 4];
  Bb[1] = *(const bf16x8*)&bp[(16 + col) * 36 + 16 + quad * 4];
  Bb[2] = *(const bf16x8*)&bp[(48 + col) * 36 + quad * 4];
  Bb[3] = *(const bf16x8*)&bp[(48 + col) * 36 + 16 + quad * 4];
  Bb[4] = *(const bf16x8*)&bp[(80 + col) * 36 + quad * 4];
  Bb[5] = *(const bf16x8*)&bp[(80 + col) * 36 + 16 + quad * 4];
  float ma0 = 0.f, ma1 = 0.f, ma2 = 0.f, ma3 = 0.f;
  float mb0 = 0.f, mb1 = 0.f, mb2 = 0.f, mb3 = 0.f;
  float sa0 = 0.f, sa1 = 0.f, sa2 = 0.f, sa3 = 0.f;
  float sb0 = 0.f, sb1 = 0.f, sb2 = 0.f, sb3 = 0.f;
  #pragma unroll
  for (int hg = 0; hg < 4; hg++) {
    f32x4 aa = (f32x4){0.f, 0.f, 0.f, 0.f};
    f32x4 ab = (f32x4){0.f, 0.f, 0.f, 0.f};
    const uint* Ab = &Wcat_l[((4 * hg + w) * 16 + col) * 96 + quad * 4];
    #pragma unroll
    for (int kt = 0; kt < 6; kt++) {
      bf16x8 Af = *(const bf16x8*)(Ab + kt * 16);
      aa = __builtin_amdgcn_mfma_f32_16x16x32_bf16(Af, Ba[kt], aa, 0, 0, 0);
      ab = __builtin_amdgcn_mfma_f32_16x16x32_bf16(Af, Bb[kt], ab, 0, 0, 0);
    }
    int ce = (4 * hg + w) * 16 + quad * 4;
    float4 be4 = ld4(be_l + ce);
    float4 at4 = ld4(attn_l + ce);
    float xa0 = aa[0] + be4.x, xa1 = aa[1] + be4.y;
    float xa2 = aa[2] + be4.z, xa3 = aa[3] + be4.w;
    float xb0 = ab[0] + be4.x, xb1 = ab[1] + be4.y;
    float xb2 = ab[2] + be4.z, xb3 = ab[3] + be4.w;
    float la0 = xa0 > 0.f ? xa0 : 0.01f * xa0;
    float la1 = xa1 > 0.f ? xa1 : 0.01f * xa1;
    float la2 = xa2 > 0.f ? xa2 : 0.01f * xa2;
    float la3 = xa3 > 0.f ? xa3 : 0.01f * xa3;
    float lb0 = xb0 > 0.f ? xb0 : 0.01f * xb0;
    float lb1 = xb1 > 0.f ? xb1 : 0.01f * xb1;
    float lb2 = xb2 > 0.f ? xb2 : 0.01f * xb2;
    float lb3 = xb3 > 0.f ? xb3 : 0.01f * xb3;
    float dpa = la0 * at4.x + la1 * at4.y + la2 * at4.z + la3 * at4.w;
    float dpb = lb0 * at4.x + lb1 * at4.y + lb2 * at4.z + lb3 * at4.w;
    if (hg == 0) { sa0 = dpa; sb0 = dpb; }
    else if (hg == 1) { sa1 = dpa; sb1 = dpb; }
    else if (hg == 2) { sa2 = dpa; sb2 = dpb; }
    else { sa3 = dpa; sb3 = dpb; }
    ma0 += xa0; ma1 += xa1; ma2 += xa2; ma3 += xa3;
    mb0 += xb0; mb1 += xb1; mb2 += xb2; mb3 += xb3;
  }
  ma0 *= 0.25f; ma1 *= 0.25f; ma2 *= 0.25f; ma3 *= 0.25f;
  mb0 *= 0.25f; mb1 *= 0.25f; mb2 *= 0.25f; mb3 *= 0.25f;
  ma[ch][0][0] = ma0; ma[ch][0][1] = ma1; ma[ch][0][2] = ma2; ma[ch][0][3] = ma3;
  ma[ch][1][0] = mb0; ma[ch][1][1] = mb1; ma[ch][1][2] = mb2; ma[ch][1][3] = mb3;
  float s1a = ma0 + ma1 + ma2 + ma3;
  float s2a = ma0*ma0 + ma1*ma1 + ma2*ma2 + ma3*ma3;
  float s1b = mb0 + mb1 + mb2 + mb3;
  float s2b = mb0*mb0 + mb1*mb1 + mb2*mb2 + mb3*mb3;
  sa0 += __shfl_xor(sa0, 16); sa0 += __shfl_xor(sa0, 32);
  sa1 += __shfl_xor(sa1, 16); sa1 += __shfl_xor(sa1, 32);
  sa2 += __shfl_xor(sa2, 16); sa2 += __shfl_xor(sa2, 32);
  sa3 += __shfl_xor(sa3, 16); sa3 += __shfl_xor(sa3, 32);
  sb0 += __shfl_xor(sb0, 16); sb0 += __shfl_xor(sb0, 32);
  sb1 += __shfl_xor(sb1, 16); sb1 += __shfl_xor(sb1, 32);
  sb2 += __shfl_xor(sb2, 16); sb2 += __shfl_xor(sb2, 32);
  sb3 += __shfl_xor(sb3, 16); sb3 += __shfl_xor(sb3, 32);
  s1a += __shfl_xor(s1a, 16); s1a += __shfl_xor(s1a, 32);
  s2a += __shfl_xor(s2a, 16); s2a += __shfl_xor(s2a, 32);
  s1b += __shfl_xor(s1b, 16); s1b += __shfl_xor(s1b, 32);
  s2b += __shfl_xor(s2b, 16); s2b += __shfl_xor(s2b, 32);
  if (quad == 0) {
    float* ra = &red[w][ch][col][0];
    ra[0] = sa0; ra[1] = sa1; ra[2] = sa2; ra[3] = sa3; ra[4] = s1a; ra[5] = s2a;
    float* rb = &red[w][ch][16 + col][0];
    rb[0] = sb0; rb[1] = sb1; rb[2] = sb2; rb[3] = sb3; rb[4] = s1b; rb[5] = s2b;
  }
}

// Persistent fused edge pass, CSR order. Each block loops over tiles (64 edges)
// with a rolling chunk pipeline: prefetch chunk c+1 gathers into regs while
// chunk c computes. Separate fout buffer; 3 syncs/tile.
__global__ __launch_bounds__(256) void edge_mfma(
    const uint4* __restrict__ f_bf, const uint4* __restrict__ h_bf,
    const uint* __restrict__ Wcat_l, const float* __restrict__ be_l,
    const float* __restrict__ attn_l, const int* __restrict__ esrc,
    const int* __restrict__ edst, float* __restrict__ scc,
    uint4* __restrict__ f_next4)
{
  __shared__ uint bstage[2][96 * 36];   // 2 x 32-edge chunk (96 rows x 144B)
  __shared__ uint fout[64 * 36];
  __shared__ float red[4][2][33][6];
  int t = threadIdx.x, lane = t & 63, w = t >> 6;
  int col = lane & 15, quad = lane >> 4;
  int sr = t >> 3, sc = t & 7;
  // initial stage: chunk (first tile, 0)
  {
    int e0 = blockIdx.x * 64 + sr;
    uint4 vs = h_bf[(long)esrc[e0] * 8 + sc];
    uint4 vd = h_bf[(long)edst[e0] * 8 + sc];
    uint4 vf = f_bf[(long)e0 * 8 + sc];
    *(uint4*)&bstage[0][sr * 36 + sc * 4] = vs;
    *(uint4*)&bstage[0][(32 + sr) * 36 + sc * 4] = vd;
    *(uint4*)&bstage[0][(64 + sr) * 36 + sc * 4] = vf;
  }
  __syncthreads();
  for (int nb = blockIdx.x; nb < EBLK; nb += GRID_E) {
    int base = nb * 64;
    int nbn = nb + GRID_E;
    float ma[2][2][4];
    // prefetch chunk (nb,1)
    int e1 = base + 32 + sr;
    uint4 p1s = h_bf[(long)esrc[e1] * 8 + sc];
    uint4 p1d = h_bf[(long)edst[e1] * 8 + sc];
    uint4 p1f = f_bf[(long)e1 * 8 + sc];
    // compute chunk 0
    edge_compute(&bstage[0][0], Wcat_l, be_l, attn_l, w, col, quad, 0, ma, red);
    // stage chunk1 from prefetch; prefetch next tile's chunk0
    *(uint4*)&bstage[1][sr * 36 + sc * 4] = p1s;
    *(uint4*)&bstage[1][(32 + sr) * 36 + sc * 4] = p1d;
    *(uint4*)&bstage[1][(64 + sr) * 36 + sc * 4] = p1f;
    int e2 = (nbn < EBLK ? nbn : nb) * 64 + sr;
    uint4 p0s = h_bf[(long)esrc[e2] * 8 + sc];
    uint4 p0d = h_bf[(long)edst[e2] * 8 + sc];
    uint4 p0f = f_bf[(long)e2 * 8 + sc];
    __syncthreads();
    // compute chunk 1
    edge_compute(&bstage[1][0], Wcat_l, be_l, attn_l, w, col, quad, 1, ma, red);
    __syncthreads();
    // epilogue: scores (coalesced), fout write, next-tile chunk0 -> bstage[0]
    {
      int eL = t >> 2, hh = t & 3;
      int chx = eL >> 5, c32 = eL & 31;
      float sv = red[0][chx][c32][hh] + red[1][chx][c32][hh]
               + red[2][chx][c32][hh] + red[3][chx][c32][hh];
      scc[(long)(base + eL) * 4 + hh] = sv;
    }
    #pragma unroll
    for (int ch = 0; ch < 2; ch++) {
      #pragma unroll
      for (int sub = 0; sub < 2; sub++) {
        int c32 = sub * 16 + col;
        float s1T = red[0][ch][c32][4] + red[1][ch][c32][4]
                  + red[2][ch][c32][4] + red[3][ch][c32][4];
        float s2T = red[0][ch][c32][5] + red[1][ch][c32][5]
                  + red[2][ch][c32][5] + red[3][ch][c32][5];
        float mean = s1T * 0.015625f;
        float var  = s2T * 0.015625f - mean * mean;
        float rs = rsqrtf(var + 1e-5f);
        float o0 = (ma[ch][sub][0] - mean) * rs; o0 = o0 > 0.f ? o0 : expm1f(o0);
        float o1 = (ma[ch][sub][1] - mean) * rs; o1 = o1 > 0.f ? o1 : expm1f(o1);
        float o2 = (ma[ch][sub][2] - mean) * rs; o2 = o2 > 0.f ? o2 : expm1f(o2);
        float o3 = (ma[ch][sub][3] - mean) * rs; o3 = o3 > 0.f ? o3 : expm1f(o3);
        int eL = ch * 32 + c32;
        fout[eL * 36 + w * 8 + quad * 2]     = packbf(o0, o1);
        fout[eL * 36 + w * 8 + quad * 2 + 1] = packbf(o2, o3);
      }
    }
    *(uint4*)&bstage[0][sr * 36 + sc * 4] = p0s;
    *(uint4*)&bstage[0][(32 + sr) * 36 + sc * 4] = p0d;
    *(uint4*)&bstage[0][(64 + sr) * 36 + sc * 4] = p0f;
    __syncthreads();
    // coalesced f_next store
    {
      int row = t >> 2, part = t & 3;
      uint4 x0 = *(uint4*)&fout[row * 36 + part * 8];
      uint4 x1 = *(uint4*)&fout[row * 36 + part * 8 + 4];
      long gp = ((long)(base + row)) * 8 + part * 2;
      f_next4[gp] = x0;
      f_next4[gp + 1] = x1;
    }
  }
}

// Fused aggregation + combine: 16 nodes/block; quarter-wave per CSR slot with
// 2-deep manual unroll (two gather chains in flight); MFMA combine + norm.
__global__ __launch_bounds__(256) void agg_combine(
    const uint2* __restrict__ h2, const float4* __restrict__ sc_csr4,
    const int* __restrict__ esrc, const int* __restrict__ off,
    const uint4* __restrict__ WcT4, const float* __restrict__ bmean_l,
    uint4* __restrict__ h_next4)
{
  __shared__ uint gsh[16][132];
  __shared__ float red2[4][17][2];
  __shared__ uint fout2[16 * 36];
  int t = threadIdx.x, lane = t & 63, w = t >> 6;
  int col = lane & 15, quad = lane >> 4;
  int n0 = blockIdx.x * 16;
  bf16x8 A2[8];
  #pragma unroll
  for (int kt = 0; kt < 8; kt++)
    A2[kt] = *(const bf16x8*)&WcT4[(w * 16 + col) * 32 + kt * 4 + quad];
  #pragma unroll 1
  for (int nl = 0; nl < 4; nl++) {
    int n = n0 + w * 4 + nl;
    int o0 = off[n], o1 = off[n + 1];
    float mx0 = -3.0e38f, mx1 = -3.0e38f, mx2 = -3.0e38f, mx3 = -3.0e38f;
    {
      int i = o0 + quad;
      for (; i + 4 < o1; i += 8) {
        float4 sA = sc_csr4[i];
        float4 sB = sc_csr4[i + 4];
        mx0 = fmaxf(mx0, fmaxf(sA.x, sB.x)); mx1 = fmaxf(mx1, fmaxf(sA.y, sB.y));
        mx2 = fmaxf(mx2, fmaxf(sA.z, sB.z)); mx3 = fmaxf(mx3, fmaxf(sA.w, sB.w));
      }
      if (i < o1) {
        float4 s = sc_csr4[i];
        mx0 = fmaxf(mx0, s.x); mx1 = fmaxf(mx1, s.y);
        mx2 = fmaxf(mx2, s.z); mx3 = fmaxf(mx3, s.w);
      }
    }
    mx0 = fmaxf(mx0, __shfl_xor(mx0, 16)); mx0 = fmaxf(mx0, __shfl_xor(mx0, 32));
    mx1 = fmaxf(mx1, __shfl_xor(mx1, 16)); mx1 = fmaxf(mx1, __shfl_xor(mx1, 32));
    mx2 = fmaxf(mx2, __shfl_xor(mx2, 16)); mx2 = fmaxf(mx2, __shfl_xor(mx2, 32));
    mx3 = fmaxf(mx3, __shfl_xor(mx3, 16)); mx3 = fmaxf(mx3, __shfl_xor(mx3, 32));
    float d0 = 0.f, d1 = 0.f, d2 = 0.f, d3 = 0.f;
    float a00=0.f,a01=0.f,a02=0.f,a03=0.f, a10=0.f,a11=0.f,a12=0.f,a13=0.f;
    float a20=0.f,a21=0.f,a22=0.f,a23=0.f, a30=0.f,a31=0.f,a32=0.f,a33=0.f;
    #define AGG_BODY(ii) { \
      float4 s = sc_csr4[ii]; \
      int sr_ = esrc[ii]; \
      uint2 hv = h2[(long)sr_ * 16 + col]; \
      float w0 = __expf(s.x - mx0), w1 = __expf(s.y - mx1); \
      float w2 = __expf(s.z - mx2), w3 = __expf(s.w - mx3); \
      d0 += w0; d1 += w1; d2 += w2; d3 += w3; \
      float4 p = up4(hv); \
      a00 = fmaf(w0,p.x,a00); a01 = fmaf(w0,p.y,a01); a02 = fmaf(w0,p.z,a02); a03 = fmaf(w0,p.w,a03); \
      a10 = fmaf(w1,p.x,a10); a11 = fmaf(w1,p.y,a11); a12 = fmaf(w1,p.z,a12); a13 = fmaf(w1,p.w,a13); \
      a20 = fmaf(w2,p.x,a20); a21 = fmaf(w2,p.y,a21); a22 = fmaf(w2,p.z,a22); a23 = fmaf(w2,p.w,a23); \
      a30 = fmaf(w3,p.x,a30); a31 = fmaf(w3,p.y,a31); a32 = fmaf(w3,p.z,a32); a33 = fmaf(w3,p.w,a33); }
    {
      int i = o0 + quad;
      for (; i + 4 < o1; i += 8) { AGG_BODY(i); AGG_BODY(i + 4); }
      if (i < o1) { AGG_BODY(i); }
    }
    #undef AGG_BODY
    d0 += __shfl_xor(d0,16); d0 += __shfl_xor(d0,32);
    d1 += __shfl_xor(d1,16); d1 += __shfl_xor(d1,32);
    d2 += __shfl_xor(d2,16); d2 += __shfl_xor(d2,32);
    d3 += __shfl_xor(d3,16); d3 += __shfl_xor(d3,32);
    a00 += __shfl_xor(a00,16); a00 += __shfl_xor(a00,32);
    a01 += __shfl_xor(a01,16); a01 += __shfl_xor(a01,32);
    a02 += __shfl_xor(a02,16); a02 += __shfl_xor(a02,32);
    a03 += __shfl_xor(a03,16); a03 += __shfl_xor(a03,32);
    a10 += __shfl_xor(a10,16); a10 += __shfl_xor(a10,32);
    a11 += __shfl_xor(a11,16); a11 += __shfl_xor(a11,32);
    a12 += __shfl_xor(a12,16); a12 += __shfl_xor(a12,32);
    a13 += __shfl_xor(a13,16); a13 += __shfl_xor(a13,32);
    a20 += __shfl_xor(a20,16); a20 += __shfl_xor(a20,32);
    a21 += __shfl_xor(a21,16); a21 += __shfl_xor(a21,32);
    a22 += __shfl_xor(a22,16); a22 += __shfl_xor(a22,32);
    a23 += __shfl_xor(a23,16); a23 += __shfl_xor(a23,32);
    a30 += __shfl_xor(a30,16); a30 += __shfl_xor(a30,32);
    a31 += __shfl_xor(a31,16); a31 += __shfl_xor(a31,32);
    a32 += __shfl_xor(a32,16); a32 += __shfl_xor(a32,32);
    a33 += __shfl_xor(a33,16); a33 += __shfl_xor(a33,32);
    uint u0 = 0u, u1 = 0u, u2 = 0u, u3 = 0u, u4 = 0u, u5 = 0u, u6 = 0u, u7 = 0u;
    if (o0 < o1) {
      float i0 = 1.f / d0, i1 = 1.f / d1, i2 = 1.f / d2, i3 = 1.f / d3;
      u0 = packbf(a00*i0, a01*i0); u1 = packbf(a02*i0, a03*i0);
      u2 = packbf(a10*i1, a11*i1); u3 = packbf(a12*i1, a13*i1);
      u4 = packbf(a20*i2, a21*i2); u5 = packbf(a22*i2, a23*i2);
      u6 = packbf(a30*i3, a31*i3); u7 = packbf(a32*i3, a33*i3);
    }
    if (quad == 0) {
      int nloc = w * 4 + nl;
      gsh[nloc][col*2]      = u0; gsh[nloc][col*2 + 1]      = u1;
      gsh[nloc][32 + col*2] = u2; gsh[nloc][32 + col*2 + 1] = u3;
      gsh[nloc][64 + col*2] = u4; gsh[nloc][64 + col*2 + 1] = u5;
      gsh[nloc][96 + col*2] = u6; gsh[nloc][96 + col*2 + 1] = u7;
    }
  }
  __syncthreads();
  f32x4 acc = (f32x4){0.f, 0.f, 0.f, 0.f};
  #pragma unroll
  for (int kt = 0; kt < 8; kt++) {
    bf16x8 Bg = *(const bf16x8*)&gsh[col][kt * 16 + quad * 4];
    acc = __builtin_amdgcn_mfma_f32_16x16x32_bf16(A2[kt], Bg, acc, 0, 0, 0);
  }
  int n2 = n0 + col;
  int dg = off[n2 + 1] - off[n2];
  float4 bm = ld4(bmean_l + w * 16 + quad * 4);
  float x0, x1, x2, x3;
  if (dg > 0) { x0 = acc[0] + bm.x; x1 = acc[1] + bm.y; x2 = acc[2] + bm.z; x3 = acc[3] + bm.w; }
  else { x0 = x1 = x2 = x3 = 0.f; }
  float s1 = x0 + x1 + x2 + x3;
  float s2 = x0*x0 + x1*x1 + x2*x2 + x3*x3;
  s1 += __shfl_xor(s1, 16); s2 += __shfl_xor(s2, 16);
  s1 += __shfl_xor(s1, 32); s2 += __shfl_xor(s2, 32);
  if (quad == 0) { red2[w][col][0] = s1; red2[w][col][1] = s2; }
  __syncthreads();
  float s1T = red2[0][col][0] + red2[1][col][0] + red2[2][col][0] + red2[3][col][0];
  float s2T = red2[0][col][1] + red2[1][col][1] + red2[2][col][1] + red2[3][col][1];
  float mean = s1T * 0.015625f;
  float var  = s2T * 0.015625f - mean * mean;
  float rs = rsqrtf(var + 1e-5f);
  float o0 = (x0 - mean) * rs; o0 = o0 > 0.f ? o0 : expm1f(o0);
  float o1 = (x1 - mean) * rs; o1 = o1 > 0.f ? o1 : expm1f(o1);
  float o2 = (x2 - mean) * rs; o2 = o2 > 0.f ? o2 : expm1f(o2);
  float o3 = (x3 - mean) * rs; o3 = o3 > 0.f ? o3 : expm1f(o3);
  fout2[col * 36 + w * 8 + quad * 2]     = packbf(o0, o1);
  fout2[col * 36 + w * 8 + quad * 2 + 1] = packbf(o2, o3);
  __syncthreads();
  if (t < 128) {
    int row = t >> 3, part = t & 7;
    uint4 x = *(uint4*)&fout2[row * 36 + part * 4];
    h_next4[((long)(n0 + row)) * 8 + part] = x;
  }
}

// out[m][j] = sum_k bf16(h)[m][k] * Wf[k][j] + bf[j]
__global__ void final_gemm(const uint2* __restrict__ h, const float* __restrict__ Wf,
                           const float* __restrict__ bf_, float* __restrict__ out) {
  int idx = blockIdx.x * 256 + threadIdx.x;
  if (idx >= NN * 16) return;
  int m = idx >> 4, j4 = (idx & 15) << 2;
  const uint2* row = h + (long)m * 16;
  float ax = 0.f, ay = 0.f, az = 0.f, aw = 0.f;
  #pragma unroll
  for (int kk = 0; kk < 16; kk++) {
    float4 a = up4(row[kk]);
    float4 b0 = ld4(Wf + (kk * 4 + 0) * 64 + j4);
    float4 b1 = ld4(Wf + (kk * 4 + 1) * 64 + j4);
    float4 b2 = ld4(Wf + (kk * 4 + 2) * 64 + j4);
    float4 b3 = ld4(Wf + (kk * 4 + 3) * 64 + j4);
    ax = fmaf(a.x, b0.x, ax); ay = fmaf(a.x, b0.y, ay); az = fmaf(a.x, b0.z, az); aw = fmaf(a.x, b0.w, aw);
    ax = fmaf(a.y, b1.x, ax); ay = fmaf(a.y, b1.y, ay); az = fmaf(a.y, b1.z, az); aw = fmaf(a.y, b1.w, aw);
    ax = fmaf(a.z, b2.x, ax); ay = fmaf(a.z, b2.y, ay); az = fmaf(a.z, b2.z, az); aw = fmaf(a.z, b2.w, aw);
    ax = fmaf(a.w, b3.x, ax); ay = fmaf(a.w, b3.y, ay); az = fmaf(a.w, b3.z, az); aw = fmaf(a.w, b3.w, aw);
  }
  float4 bb = ld4(bf_ + j4);
  *(float4*)(out + (long)m * 64 + j4) = make_float4(ax + bb.x, ay + bb.y, az + bb.z, aw + bb.w);
}

extern "C" void kernel_launch(void* const* d_in, const int* in_sizes, int n_in,
                              void* d_out, int out_size, void* d_ws, size_t ws_size,
                              hipStream_t stream) {
  const float* x      = (const float*)d_in[0];
  const float* efeat  = (const float*)d_in[1];
  const int*   src    = (const int*)d_in[2];
  const int*   dst    = (const int*)d_in[3];
  const float* Wn0    = (const float*)d_in[4];
  const float* bn0    = (const float*)d_in[5];
  const float* We0    = (const float*)d_in[6];
  const float* be0    = (const float*)d_in[7];
  const float* Wnode  = (const float*)d_in[8];
  const float* bnode  = (const float*)d_in[9];
  const float* Wni    = (const float*)d_in[10];
  const float* Wnj    = (const float*)d_in[11];
  const float* Wfij   = (const float*)d_in[12];
  const float* attn   = (const float*)d_in[13];
  const float* bias_e = (const float*)d_in[14];
  const float* Wf     = (const float*)d_in[15];
  const float* bf     = (const float*)d_in[16];
  float* out = (float*)d_out;

  char* w = (char*)d_ws;
  auto alloc = [&](size_t nbytes) { char* p = w; w += (nbytes + 255) & ~(size_t)255; return p; };
  uint2* h_a   = (uint2*)alloc((size_t)NN * 128);    // bf16 [NN][64]
  uint2* h_b   = (uint2*)alloc((size_t)NN * 128);
  uint2* f_a   = (uint2*)alloc((size_t)NE * 128);    // bf16 [NE][64], CSR edge order
  uint2* f_b   = (uint2*)alloc((size_t)NE * 128);
  float* scc   = (float*)alloc((size_t)NE * 16);     // scores, CSR order [E][4]
  uint*  Wcat  = (uint*)alloc((size_t)2 * 24576 * 4);
  uint*  WcT   = (uint*)alloc((size_t)2 * 8192 * 4);
  float* bmean = (float*)alloc((size_t)2 * 64 * 4);
  int* deg     = (int*)alloc((size_t)NN * 2 * 4);
  int* cursor  = deg + NN;
  int* off     = (int*)alloc((size_t)(NN + 1) * 4);
  int* esrc    = (int*)alloc((size_t)NE * 4);
  int* edst    = (int*)alloc((size_t)NE * 4);
  int* csr_pos = (int*)alloc((size_t)NE * 4);
  int* bsum    = (int*)alloc((size_t)128 * 4);

  zero_i32<<<(2 * NN + 255) / 256, 256, 0, stream>>>(deg, 2 * NN);
  count_deg<<<(NE + 255) / 256, 256, 0, stream>>>(dst, deg);
  scan1<<<SCAN_BLOCKS, 256, 0, stream>>>(deg, off, bsum);
  scan2<<<1, 128, 0, stream>>>(bsum, off);
  scan3<<<SCAN_BLOCKS, 256, 0, stream>>>(off, bsum);
  fill_csr<<<(NE + 255) / 256, 256, 0, stream>>>(dst, src, off, cursor, esrc, edst, csr_pos);

  gemm16_bf16<65><<<(NN * 4 + 255) / 256, 256, 0, stream>>>(x, Wn0, bn0, h_a, NN, nullptr);
  gemm16_bf16<15><<<(NE * 4 + 255) / 256, 256, 0, stream>>>(efeat, We0, be0, f_a, NE, csr_pos);
  prep_w<<<4, 256, 0, stream>>>(Wni, Wnj, Wfij, Wnode, bnode, Wcat, WcT, bmean);

  uint2* hc = h_a; uint2* hn = h_b;
  uint2* fc = f_a; uint2* fn = f_b;
  for (int l = 0; l < 2; l++) {
    const uint* Wcat_l = Wcat + (size_t)l * 24576;
    const uint4* WcT_l = (const uint4*)(WcT + (size_t)l * 8192);
    const float* bm_l  = bmean + (size_t)l * 64;
    const float* be_l  = bias_e + (size_t)l * 256;
    const float* at_l  = attn + (size_t)l * 256;
    edge_mfma<<<GRID_E, 256, 0, stream>>>((const uint4*)fc, (const uint4*)hc,
                                          Wcat_l, be_l, at_l, esrc, edst, scc,
                                          (uint4*)fn);
    agg_combine<<<NN / 16, 256, 0, stream>>>((const uint2*)hc, (const float4*)scc,
                                             esrc, off, WcT_l, bm_l, (uint4*)hn);
    uint2* tmp = hc; hc = hn; hn = tmp;
    tmp = fc; fc = fn; fn = tmp;
  }
  final_gemm<<<(NN * 16 + 255) / 256, 256, 0, stream>>>(hc, Wf, bf, out);
}

// Round 12
// 421.108 us; speedup vs baseline: 1.9626x; 1.9626x over previous
//
#include <hip/hip_runtime.h>
#include <cmath>

#define NN 20000
#define NE 200000
#define SCAN_BLOCKS 79   // ceil(NN/256)
#define EBLK 3125        // NE/64
#define GRID_E 768       // persistent edge grid: 3 blocks/CU

typedef __attribute__((ext_vector_type(8))) short bf16x8;
typedef __attribute__((ext_vector_type(4))) float f32x4;
typedef unsigned int uint;

__device__ __forceinline__ float4 ld4(const float* p){ return *(const float4*)p; }

// RNE float->bf16
__device__ __forceinline__ uint packbf(float a, float b) {
  uint ua = __float_as_uint(a);
  uint ub = __float_as_uint(b);
  ua = (ua + 0x7fffu + ((ua >> 16) & 1u)) >> 16;
  ub = (ub + 0x7fffu + ((ub >> 16) & 1u)) >> 16;
  return ua | (ub << 16);
}
__device__ __forceinline__ float4 up4(uint2 u) {
  return make_float4(__uint_as_float(u.x << 16), __uint_as_float(u.x & 0xffff0000u),
                     __uint_as_float(u.y << 16), __uint_as_float(u.y & 0xffff0000u));
}

// GEMM -> packed bf16, 16 ch/thread; runtime K (rolled loop — no spills);
// optional output-row permutation (map).
__global__ void gemm16_bf16(const float* __restrict__ A, const float* __restrict__ B,
                            const float* __restrict__ bias, uint2* __restrict__ O,
                            int M, int K, const int* __restrict__ map) {
  int idx = blockIdx.x * 256 + threadIdx.x;
  if (idx >= M * 4) return;
  int m = idx >> 2, jq = idx & 3;
  const float* a = A + (long)m * K;
  const float* b = B + jq * 16;
  float c00=0,c01=0,c02=0,c03=0,c04=0,c05=0,c06=0,c07=0;
  float c08=0,c09=0,c10=0,c11=0,c12=0,c13=0,c14=0,c15=0;
  for (int k = 0; k < K; k++) {
    float av = a[k];
    const float* br = b + (long)k * 64;
    float4 b0 = ld4(br), b1 = ld4(br + 4), b2 = ld4(br + 8), b3 = ld4(br + 12);
    c00 = fmaf(av, b0.x, c00); c01 = fmaf(av, b0.y, c01); c02 = fmaf(av, b0.z, c02); c03 = fmaf(av, b0.w, c03);
    c04 = fmaf(av, b1.x, c04); c05 = fmaf(av, b1.y, c05); c06 = fmaf(av, b1.z, c06); c07 = fmaf(av, b1.w, c07);
    c08 = fmaf(av, b2.x, c08); c09 = fmaf(av, b2.y, c09); c10 = fmaf(av, b2.z, c10); c11 = fmaf(av, b2.w, c11);
    c12 = fmaf(av, b3.x, c12); c13 = fmaf(av, b3.y, c13); c14 = fmaf(av, b3.z, c14); c15 = fmaf(av, b3.w, c15);
  }
  const float* bb = bias + jq * 16;
  float4 v0 = ld4(bb), v1 = ld4(bb + 4), v2 = ld4(bb + 8), v3 = ld4(bb + 12);
  int mo = map ? map[m] : m;
  uint2* op = O + (long)mo * 16 + jq * 4;
  op[0] = make_uint2(packbf(c00 + v0.x, c01 + v0.y), packbf(c02 + v0.z, c03 + v0.w));
  op[1] = make_uint2(packbf(c04 + v1.x, c05 + v1.y), packbf(c06 + v1.z, c07 + v1.w));
  op[2] = make_uint2(packbf(c08 + v2.x, c09 + v2.y), packbf(c10 + v2.z, c11 + v2.w));
  op[3] = make_uint2(packbf(c12 + v3.x, c13 + v3.y), packbf(c14 + v3.z, c15 + v3.w));
}

__global__ void zero_i32(int* __restrict__ p, int n) {
  int i = blockIdx.x * 256 + threadIdx.x;
  if (i < n) p[i] = 0;
}

__global__ void count_deg(const int* __restrict__ dst, int* __restrict__ deg) {
  int e = blockIdx.x * 256 + threadIdx.x;
  if (e < NE) atomicAdd(&deg[dst[e]], 1);
}

__global__ void scan1(const int* __restrict__ deg, int* __restrict__ off, int* __restrict__ bsum) {
  __shared__ int buf[256];
  int t = threadIdx.x;
  int g = blockIdx.x * 256 + t;
  int v = (g < NN) ? deg[g] : 0;
  buf[t] = v;
  __syncthreads();
  for (int s = 1; s < 256; s <<= 1) {
    int x = (t >= s) ? buf[t - s] : 0;
    __syncthreads();
    buf[t] += x;
    __syncthreads();
  }
  if (g < NN) off[g] = buf[t] - v;
  if (t == 255) bsum[blockIdx.x] = buf[255];
}

__global__ void scan2(int* __restrict__ bsum, int* __restrict__ off) {
  __shared__ int buf[128];
  int t = threadIdx.x;
  int v = (t < SCAN_BLOCKS) ? bsum[t] : 0;
  buf[t] = v;
  __syncthreads();
  for (int s = 1; s < 128; s <<= 1) {
    int x = (t >= s) ? buf[t - s] : 0;
    __syncthreads();
    buf[t] += x;
    __syncthreads();
  }
  if (t < SCAN_BLOCKS) bsum[t] = buf[t] - v;
  if (t == 127) off[NN] = buf[127];
}

__global__ void scan3(int* __restrict__ off, const int* __restrict__ bsum) {
  int g = blockIdx.x * 256 + threadIdx.x;
  if (g < NN) off[g] += bsum[blockIdx.x];
}

__global__ void fill_csr(const int* __restrict__ dst, const int* __restrict__ src,
                         const int* __restrict__ off, int* __restrict__ cursor,
                         int* __restrict__ esrc, int* __restrict__ edst,
                         int* __restrict__ csr_pos) {
  int e = blockIdx.x * 256 + threadIdx.x;
  if (e >= NE) return;
  int d = dst[e];
  int p = atomicAdd(&cursor[d], 1);
  int pos = off[d] + p;
  esrc[pos] = src[e];
  edst[pos] = d;
  csr_pos[e] = pos;
}

// Wcat[l][c][k] bf16 (k<192 = Wni|Wnj|Wfij cols), WcT[l][c<64][k<256] = Wnode[kk][h*64+c]/4,
// bmean[l][c<64] = mean_h bnode.
__global__ void prep_w(const float* __restrict__ Wni, const float* __restrict__ Wnj,
                       const float* __restrict__ Wfij, const float* __restrict__ Wnode,
                       const float* __restrict__ bnode,
                       uint* __restrict__ Wcat, uint* __restrict__ WcT,
                       float* __restrict__ bmean) {
  int rid = blockIdx.x * 256 + threadIdx.x;
  if (rid < 512) {
    int l = rid >> 8, c = rid & 255;
    uint* D = Wcat + (size_t)l * 24576 + c * 96;
    for (int k8 = 0; k8 < 24; k8++) {
      int ss = k8 >> 3;
      const float* S = (ss == 0 ? Wni : ss == 1 ? Wnj : Wfij) + l * 16384;
      int kl = (k8 & 7) * 8;
      uint u0 = packbf(S[(kl+0)*256 + c], S[(kl+1)*256 + c]);
      uint u1 = packbf(S[(kl+2)*256 + c], S[(kl+3)*256 + c]);
      uint u2 = packbf(S[(kl+4)*256 + c], S[(kl+5)*256 + c]);
      uint u3 = packbf(S[(kl+6)*256 + c], S[(kl+7)*256 + c]);
      *((uint4*)(D + k8 * 4)) = make_uint4(u0, u1, u2, u3);
    }
  } else if (rid < 640) {
    int idx = rid - 512;
    int l = idx >> 6, c = idx & 63;
    const float* S = Wnode + l * 16384;
    uint* D = WcT + (size_t)l * 8192 + c * 128;
    for (int kp = 0; kp < 128; kp++) {
      int k0 = kp * 2, k1 = kp * 2 + 1;
      float v0 = S[(k0 & 63) * 256 + (k0 >> 6) * 64 + c] * 0.25f;
      float v1 = S[(k1 & 63) * 256 + (k1 >> 6) * 64 + c] * 0.25f;
      D[kp] = packbf(v0, v1);
    }
  } else if (rid < 768) {
    int idx = rid - 640;
    int l = idx >> 6, c = idx & 63;
    const float* S = bnode + l * 256;
    bmean[l * 64 + c] = 0.25f * (S[c] + S[64 + c] + S[128 + c] + S[192 + c]);
  }
}

// compute one 32-edge chunk (two 16-edge B-subtiles) from staged LDS buffer bp
__device__ __forceinline__ void edge_compute(
    const uint* bp, const uint* __restrict__ Wcat_l,
    const float* __restrict__ be_l, const float* __restrict__ attn_l,
    int w, int col, int quad, int ch,
    float (&ma)[2][2][4], float (&red)[4][2][33][6])
{
  bf16x8 Ba[6], Bb[6];
  Ba[0] = *(const bf16x8*)&bp[col * 36 + quad * 4];
  Ba[1] = *(const bf16x8*)&bp[col * 36 + 16 + quad * 4];
  Ba[2] = *(const bf16x8*)&bp[(32 + col) * 36 + quad * 4];
  Ba[3] = *(const bf16x8*)&bp[(32 + col) * 36 + 16 + quad * 4];
  Ba[4] = *(const bf16x8*)&bp[(64 + col) * 36 + quad * 4];
  Ba[5] = *(const bf16x8*)&bp[(64 + col) * 36 + 16 + quad * 4];
  Bb[0] = *(const bf16x8*)&bp[(16 + col) * 36 + quad * 4];
  Bb[1] = *(const bf16x8*)&bp[(16 + col) * 36 + 16 + quad * 4];
  Bb[2] = *(const bf16x8*)&bp[(48 + col) * 36 + quad * 4];
  Bb[3] = *(const bf16x8*)&bp[(48 + col) * 36 + 16 + quad * 4];
  Bb[4] = *(const bf16x8*)&bp[(80 + col) * 36 + quad * 4];
  Bb[5] = *(const bf16x8*)&bp[(80 + col) * 36 + 16 + quad * 4];
  float ma0 = 0.f, ma1 = 0.f, ma2 = 0.f, ma3 = 0.f;
  float mb0 = 0.f, mb1 = 0.f, mb2 = 0.f, mb3 = 0.f;
  float sa0 = 0.f, sa1 = 0.f, sa2 = 0.f, sa3 = 0.f;
  float sb0 = 0.f, sb1 = 0.f, sb2 = 0.f, sb3 = 0.f;
  #pragma unroll
  for (int hg = 0; hg < 4; hg++) {
    f32x4 aa = (f32x4){0.f, 0.f, 0.f, 0.f};
    f32x4 ab = (f32x4){0.f, 0.f, 0.f, 0.f};
    const uint* Ab = &Wcat_l[((4 * hg + w) * 16 + col) * 96 + quad * 4];
    #pragma unroll
    for (int kt = 0; kt < 6; kt++) {
      bf16x8 Af = *(const bf16x8*)(Ab + kt * 16);
      aa = __builtin_amdgcn_mfma_f32_16x16x32_bf16(Af, Ba[kt], aa, 0, 0, 0);
      ab = __builtin_amdgcn_mfma_f32_16x16x32_bf16(Af, Bb[kt], ab, 0, 0, 0);
    }
    int ce = (4 * hg + w) * 16 + quad * 4;
    float4 be4 = ld4(be_l + ce);
    float4 at4 = ld4(attn_l + ce);
    float xa0 = aa[0] + be4.x, xa1 = aa[1] + be4.y;
    float xa2 = aa[2] + be4.z, xa3 = aa[3] + be4.w;
    float xb0 = ab[0] + be4.x, xb1 = ab[1] + be4.y;
    float xb2 = ab[2] + be4.z, xb3 = ab[3] + be4.w;
    float la0 = xa0 > 0.f ? xa0 : 0.01f * xa0;
    float la1 = xa1 > 0.f ? xa1 : 0.01f * xa1;
    float la2 = xa2 > 0.f ? xa2 : 0.01f * xa2;
    float la3 = xa3 > 0.f ? xa3 : 0.01f * xa3;
    float lb0 = xb0 > 0.f ? xb0 : 0.01f * xb0;
    float lb1 = xb1 > 0.f ? xb1 : 0.01f * xb1;
    float lb2 = xb2 > 0.f ? xb2 : 0.01f * xb2;
    float lb3 = xb3 > 0.f ? xb3 : 0.01f * xb3;
    float dpa = la0 * at4.x + la1 * at4.y + la2 * at4.z + la3 * at4.w;
    float dpb = lb0 * at4.x + lb1 * at4.y + lb2 * at4.z + lb3 * at4.w;
    if (hg == 0) { sa0 = dpa; sb0 = dpb; }
    else if (hg == 1) { sa1 = dpa; sb1 = dpb; }
    else if (hg == 2) { sa2 = dpa; sb2 = dpb; }
    else { sa3 = dpa; sb3 = dpb; }
    ma0 += xa0; ma1 += xa1; ma2 += xa2; ma3 += xa3;
    mb0 += xb0; mb1 += xb1; mb2 += xb2; mb3 += xb3;
  }
  ma0 *= 0.25f; ma1 *= 0.25f; ma2 *= 0.25f; ma3 *= 0.25f;
  mb0 *= 0.25f; mb1 *= 0.25f; mb2 *= 0.25f; mb3 *= 0.25f;
  ma[ch][0][0] = ma0; ma[ch][0][1] = ma1; ma[ch][0][2] = ma2; ma[ch][0][3] = ma3;
  ma[ch][1][0] = mb0; ma[ch][1][1] = mb1; ma[ch][1][2] = mb2; ma[ch][1][3] = mb3;
  float s1a = ma0 + ma1 + ma2 + ma3;
  float s2a = ma0*ma0 + ma1*ma1 + ma2*ma2 + ma3*ma3;
  float s1b = mb0 + mb1 + mb2 + mb3;
  float s2b = mb0*mb0 + mb1*mb1 + mb2*mb2 + mb3*mb3;
  sa0 += __shfl_xor(sa0, 16); sa0 += __shfl_xor(sa0, 32);
  sa1 += __shfl_xor(sa1, 16); sa1 += __shfl_xor(sa1, 32);
  sa2 += __shfl_xor(sa2, 16); sa2 += __shfl_xor(sa2, 32);
  sa3 += __shfl_xor(sa3, 16); sa3 += __shfl_xor(sa3, 32);
  sb0 += __shfl_xor(sb0, 16); sb0 += __shfl_xor(sb0, 32);
  sb1 += __shfl_xor(sb1, 16); sb1 += __shfl_xor(sb1, 32);
  sb2 += __shfl_xor(sb2, 16); sb2 += __shfl_xor(sb2, 32);
  sb3 += __shfl_xor(sb3, 16); sb3 += __shfl_xor(sb3, 32);
  s1a += __shfl_xor(s1a, 16); s1a += __shfl_xor(s1a, 32);
  s2a += __shfl_xor(s2a, 16); s2a += __shfl_xor(s2a, 32);
  s1b += __shfl_xor(s1b, 16); s1b += __shfl_xor(s1b, 32);
  s2b += __shfl_xor(s2b, 16); s2b += __shfl_xor(s2b, 32);
  if (quad == 0) {
    float* ra = &red[w][ch][col][0];
    ra[0] = sa0; ra[1] = sa1; ra[2] = sa2; ra[3] = sa3; ra[4] = s1a; ra[5] = s2a;
    float* rb = &red[w][ch][16 + col][0];
    rb[0] = sb0; rb[1] = sb1; rb[2] = sb2; rb[3] = sb3; rb[4] = s1b; rb[5] = s2b;
  }
}

// Persistent fused edge pass, CSR order. Each block loops over tiles (64 edges)
// with a rolling chunk pipeline: prefetch chunk c+1 gathers into regs while
// chunk c computes. Separate fout buffer; 3 syncs/tile.
__global__ __launch_bounds__(256) void edge_mfma(
    const uint4* __restrict__ f_bf, const uint4* __restrict__ h_bf,
    const uint* __restrict__ Wcat_l, const float* __restrict__ be_l,
    const float* __restrict__ attn_l, const int* __restrict__ esrc,
    const int* __restrict__ edst, float* __restrict__ scc,
    uint4* __restrict__ f_next4)
{
  __shared__ uint bstage[2][96 * 36];   // 2 x 32-edge chunk (96 rows x 144B)
  __shared__ uint fout[64 * 36];
  __shared__ float red[4][2][33][6];
  int t = threadIdx.x, lane = t & 63, w = t >> 6;
  int col = lane & 15, quad = lane >> 4;
  int sr = t >> 3, sc = t & 7;
  // initial stage: chunk (first tile, 0)
  {
    int e0 = blockIdx.x * 64 + sr;
    uint4 vs = h_bf[(long)esrc[e0] * 8 + sc];
    uint4 vd = h_bf[(long)edst[e0] * 8 + sc];
    uint4 vf = f_bf[(long)e0 * 8 + sc];
    *(uint4*)&bstage[0][sr * 36 + sc * 4] = vs;
    *(uint4*)&bstage[0][(32 + sr) * 36 + sc * 4] = vd;
    *(uint4*)&bstage[0][(64 + sr) * 36 + sc * 4] = vf;
  }
  __syncthreads();
  for (int nb = blockIdx.x; nb < EBLK; nb += GRID_E) {
    int base = nb * 64;
    int nbn = nb + GRID_E;
    float ma[2][2][4];
    // prefetch chunk (nb,1)
    int e1 = base + 32 + sr;
    uint4 p1s = h_bf[(long)esrc[e1] * 8 + sc];
    uint4 p1d = h_bf[(long)edst[e1] * 8 + sc];
    uint4 p1f = f_bf[(long)e1 * 8 + sc];
    // compute chunk 0
    edge_compute(&bstage[0][0], Wcat_l, be_l, attn_l, w, col, quad, 0, ma, red);
    // stage chunk1 from prefetch; prefetch next tile's chunk0
    *(uint4*)&bstage[1][sr * 36 + sc * 4] = p1s;
    *(uint4*)&bstage[1][(32 + sr) * 36 + sc * 4] = p1d;
    *(uint4*)&bstage[1][(64 + sr) * 36 + sc * 4] = p1f;
    int e2 = (nbn < EBLK ? nbn : nb) * 64 + sr;
    uint4 p0s = h_bf[(long)esrc[e2] * 8 + sc];
    uint4 p0d = h_bf[(long)edst[e2] * 8 + sc];
    uint4 p0f = f_bf[(long)e2 * 8 + sc];
    __syncthreads();
    // compute chunk 1
    edge_compute(&bstage[1][0], Wcat_l, be_l, attn_l, w, col, quad, 1, ma, red);
    __syncthreads();
    // epilogue: scores (coalesced), fout write, next-tile chunk0 -> bstage[0]
    {
      int eL = t >> 2, hh = t & 3;
      int chx = eL >> 5, c32 = eL & 31;
      float sv = red[0][chx][c32][hh] + red[1][chx][c32][hh]
               + red[2][chx][c32][hh] + red[3][chx][c32][hh];
      scc[(long)(base + eL) * 4 + hh] = sv;
    }
    #pragma unroll
    for (int ch = 0; ch < 2; ch++) {
      #pragma unroll
      for (int sub = 0; sub < 2; sub++) {
        int c32 = sub * 16 + col;
        float s1T = red[0][ch][c32][4] + red[1][ch][c32][4]
                  + red[2][ch][c32][4] + red[3][ch][c32][4];
        float s2T = red[0][ch][c32][5] + red[1][ch][c32][5]
                  + red[2][ch][c32][5] + red[3][ch][c32][5];
        float mean = s1T * 0.015625f;
        float var  = s2T * 0.015625f - mean * mean;
        float rs = rsqrtf(var + 1e-5f);
        float o0 = (ma[ch][sub][0] - mean) * rs; o0 = o0 > 0.f ? o0 : expm1f(o0);
        float o1 = (ma[ch][sub][1] - mean) * rs; o1 = o1 > 0.f ? o1 : expm1f(o1);
        float o2 = (ma[ch][sub][2] - mean) * rs; o2 = o2 > 0.f ? o2 : expm1f(o2);
        float o3 = (ma[ch][sub][3] - mean) * rs; o3 = o3 > 0.f ? o3 : expm1f(o3);
        int eL = ch * 32 + c32;
        fout[eL * 36 + w * 8 + quad * 2]     = packbf(o0, o1);
        fout[eL * 36 + w * 8 + quad * 2 + 1] = packbf(o2, o3);
      }
    }
    *(uint4*)&bstage[0][sr * 36 + sc * 4] = p0s;
    *(uint4*)&bstage[0][(32 + sr) * 36 + sc * 4] = p0d;
    *(uint4*)&bstage[0][(64 + sr) * 36 + sc * 4] = p0f;
    __syncthreads();
    // coalesced f_next store
    {
      int row = t >> 2, part = t & 3;
      uint4 x0 = *(uint4*)&fout[row * 36 + part * 8];
      uint4 x1 = *(uint4*)&fout[row * 36 + part * 8 + 4];
      long gp = ((long)(base + row)) * 8 + part * 2;
      f_next4[gp] = x0;
      f_next4[gp + 1] = x1;
    }
  }
}

// Fused aggregation + combine: 16 nodes/block; quarter-wave per CSR slot with
// 2-deep manual unroll (two gather chains in flight); MFMA combine + norm.
__global__ __launch_bounds__(256) void agg_combine(
    const uint2* __restrict__ h2, const float4* __restrict__ sc_csr4,
    const int* __restrict__ esrc, const int* __restrict__ off,
    const uint4* __restrict__ WcT4, const float* __restrict__ bmean_l,
    uint4* __restrict__ h_next4)
{
  __shared__ uint gsh[16][132];
  __shared__ float red2[4][17][2];
  __shared__ uint fout2[16 * 36];
  int t = threadIdx.x, lane = t & 63, w = t >> 6;
  int col = lane & 15, quad = lane >> 4;
  int n0 = blockIdx.x * 16;
  bf16x8 A2[8];
  #pragma unroll
  for (int kt = 0; kt < 8; kt++)
    A2[kt] = *(const bf16x8*)&WcT4[(w * 16 + col) * 32 + kt * 4 + quad];
  #pragma unroll 1
  for (int nl = 0; nl < 4; nl++) {
    int n = n0 + w * 4 + nl;
    int o0 = off[n], o1 = off[n + 1];
    float mx0 = -3.0e38f, mx1 = -3.0e38f, mx2 = -3.0e38f, mx3 = -3.0e38f;
    {
      int i = o0 + quad;
      for (; i + 4 < o1; i += 8) {
        float4 sA = sc_csr4[i];
        float4 sB = sc_csr4[i + 4];
        mx0 = fmaxf(mx0, fmaxf(sA.x, sB.x)); mx1 = fmaxf(mx1, fmaxf(sA.y, sB.y));
        mx2 = fmaxf(mx2, fmaxf(sA.z, sB.z)); mx3 = fmaxf(mx3, fmaxf(sA.w, sB.w));
      }
      if (i < o1) {
        float4 s = sc_csr4[i];
        mx0 = fmaxf(mx0, s.x); mx1 = fmaxf(mx1, s.y);
        mx2 = fmaxf(mx2, s.z); mx3 = fmaxf(mx3, s.w);
      }
    }
    mx0 = fmaxf(mx0, __shfl_xor(mx0, 16)); mx0 = fmaxf(mx0, __shfl_xor(mx0, 32));
    mx1 = fmaxf(mx1, __shfl_xor(mx1, 16)); mx1 = fmaxf(mx1, __shfl_xor(mx1, 32));
    mx2 = fmaxf(mx2, __shfl_xor(mx2, 16)); mx2 = fmaxf(mx2, __shfl_xor(mx2, 32));
    mx3 = fmaxf(mx3, __shfl_xor(mx3, 16)); mx3 = fmaxf(mx3, __shfl_xor(mx3, 32));
    float d0 = 0.f, d1 = 0.f, d2 = 0.f, d3 = 0.f;
    float a00=0.f,a01=0.f,a02=0.f,a03=0.f, a10=0.f,a11=0.f,a12=0.f,a13=0.f;
    float a20=0.f,a21=0.f,a22=0.f,a23=0.f, a30=0.f,a31=0.f,a32=0.f,a33=0.f;
    #define AGG_BODY(ii) { \
      float4 s = sc_csr4[ii]; \
      int sr_ = esrc[ii]; \
      uint2 hv = h2[(long)sr_ * 16 + col]; \
      float w0 = __expf(s.x - mx0), w1 = __expf(s.y - mx1); \
      float w2 = __expf(s.z - mx2), w3 = __expf(s.w - mx3); \
      d0 += w0; d1 += w1; d2 += w2; d3 += w3; \
      float4 p = up4(hv); \
      a00 = fmaf(w0,p.x,a00); a01 = fmaf(w0,p.y,a01); a02 = fmaf(w0,p.z,a02); a03 = fmaf(w0,p.w,a03); \
      a10 = fmaf(w1,p.x,a10); a11 = fmaf(w1,p.y,a11); a12 = fmaf(w1,p.z,a12); a13 = fmaf(w1,p.w,a13); \
      a20 = fmaf(w2,p.x,a20); a21 = fmaf(w2,p.y,a21); a22 = fmaf(w2,p.z,a22); a23 = fmaf(w2,p.w,a23); \
      a30 = fmaf(w3,p.x,a30); a31 = fmaf(w3,p.y,a31); a32 = fmaf(w3,p.z,a32); a33 = fmaf(w3,p.w,a33); }
    {
      int i = o0 + quad;
      for (; i + 4 < o1; i += 8) { AGG_BODY(i); AGG_BODY(i + 4); }
      if (i < o1) { AGG_BODY(i); }
    }
    #undef AGG_BODY
    d0 += __shfl_xor(d0,16); d0 += __shfl_xor(d0,32);
    d1 += __shfl_xor(d1,16); d1 += __shfl_xor(d1,32);
    d2 += __shfl_xor(d2,16); d2 += __shfl_xor(d2,32);
    d3 += __shfl_xor(d3,16); d3 += __shfl_xor(d3,32);
    a00 += __shfl_xor(a00,16); a00 += __shfl_xor(a00,32);
    a01 += __shfl_xor(a01,16); a01 += __shfl_xor(a01,32);
    a02 += __shfl_xor(a02,16); a02 += __shfl_xor(a02,32);
    a03 += __shfl_xor(a03,16); a03 += __shfl_xor(a03,32);
    a10 += __shfl_xor(a10,16); a10 += __shfl_xor(a10,32);
    a11 += __shfl_xor(a11,16); a11 += __shfl_xor(a11,32);
    a12 += __shfl_xor(a12,16); a12 += __shfl_xor(a12,32);
    a13 += __shfl_xor(a13,16); a13 += __shfl_xor(a13,32);
    a20 += __shfl_xor(a20,16); a20 += __shfl_xor(a20,32);
    a21 += __shfl_xor(a21,16); a21 += __shfl_xor(a21,32);
    a22 += __shfl_xor(a22,16); a22 += __shfl_xor(a22,32);
    a23 += __shfl_xor(a23,16); a23 += __shfl_xor(a23,32);
    a30 += __shfl_xor(a30,16); a30 += __shfl_xor(a30,32);
    a31 += __shfl_xor(a31,16); a31 += __shfl_xor(a31,32);
    a32 += __shfl_xor(a32,16); a32 += __shfl_xor(a32,32);
    a33 += __shfl_xor(a33,16); a33 += __shfl_xor(a33,32);
    uint u0 = 0u, u1 = 0u, u2 = 0u, u3 = 0u, u4 = 0u, u5 = 0u, u6 = 0u, u7 = 0u;
    if (o0 < o1) {
      float i0 = 1.f / d0, i1 = 1.f / d1, i2 = 1.f / d2, i3 = 1.f / d3;
      u0 = packbf(a00*i0, a01*i0); u1 = packbf(a02*i0, a03*i0);
      u2 = packbf(a10*i1, a11*i1); u3 = packbf(a12*i1, a13*i1);
      u4 = packbf(a20*i2, a21*i2); u5 = packbf(a22*i2, a23*i2);
      u6 = packbf(a30*i3, a31*i3); u7 = packbf(a32*i3, a33*i3);
    }
    if (quad == 0) {
      int nloc = w * 4 + nl;
      gsh[nloc][col*2]      = u0; gsh[nloc][col*2 + 1]      = u1;
      gsh[nloc][32 + col*2] = u2; gsh[nloc][32 + col*2 + 1] = u3;
      gsh[nloc][64 + col*2] = u4; gsh[nloc][64 + col*2 + 1] = u5;
      gsh[nloc][96 + col*2] = u6; gsh[nloc][96 + col*2 + 1] = u7;
    }
  }
  __syncthreads();
  f32x4 acc = (f32x4){0.f, 0.f, 0.f, 0.f};
  #pragma unroll
  for (int kt = 0; kt < 8; kt++) {
    bf16x8 Bg = *(const bf16x8*)&gsh[col][kt * 16 + quad * 4];
    acc = __builtin_amdgcn_mfma_f32_16x16x32_bf16(A2[kt], Bg, acc, 0, 0, 0);
  }
  int n2 = n0 + col;
  int dg = off[n2 + 1] - off[n2];
  float4 bm = ld4(bmean_l + w * 16 + quad * 4);
  float x0, x1, x2, x3;
  if (dg > 0) { x0 = acc[0] + bm.x; x1 = acc[1] + bm.y; x2 = acc[2] + bm.z; x3 = acc[3] + bm.w; }
  else { x0 = x1 = x2 = x3 = 0.f; }
  float s1 = x0 + x1 + x2 + x3;
  float s2 = x0*x0 + x1*x1 + x2*x2 + x3*x3;
  s1 += __shfl_xor(s1, 16); s2 += __shfl_xor(s2, 16);
  s1 += __shfl_xor(s1, 32); s2 += __shfl_xor(s2, 32);
  if (quad == 0) { red2[w][col][0] = s1; red2[w][col][1] = s2; }
  __syncthreads();
  float s1T = red2[0][col][0] + red2[1][col][0] + red2[2][col][0] + red2[3][col][0];
  float s2T = red2[0][col][1] + red2[1][col][1] + red2[2][col][1] + red2[3][col][1];
  float mean = s1T * 0.015625f;
  float var  = s2T * 0.015625f - mean * mean;
  float rs = rsqrtf(var + 1e-5f);
  float o0 = (x0 - mean) * rs; o0 = o0 > 0.f ? o0 : expm1f(o0);
  float o1 = (x1 - mean) * rs; o1 = o1 > 0.f ? o1 : expm1f(o1);
  float o2 = (x2 - mean) * rs; o2 = o2 > 0.f ? o2 : expm1f(o2);
  float o3 = (x3 - mean) * rs; o3 = o3 > 0.f ? o3 : expm1f(o3);
  fout2[col * 36 + w * 8 + quad * 2]     = packbf(o0, o1);
  fout2[col * 36 + w * 8 + quad * 2 + 1] = packbf(o2, o3);
  __syncthreads();
  if (t < 128) {
    int row = t >> 3, part = t & 7;
    uint4 x = *(uint4*)&fout2[row * 36 + part * 4];
    h_next4[((long)(n0 + row)) * 8 + part] = x;
  }
}

// out[m][j] = sum_k bf16(h)[m][k] * Wf[k][j] + bf[j]
__global__ void final_gemm(const uint2* __restrict__ h, const float* __restrict__ Wf,
                           const float* __restrict__ bf_, float* __restrict__ out) {
  int idx = blockIdx.x * 256 + threadIdx.x;
  if (idx >= NN * 16) return;
  int m = idx >> 4, j4 = (idx & 15) << 2;
  const uint2* row = h + (long)m * 16;
  float ax = 0.f, ay = 0.f, az = 0.f, aw = 0.f;
  for (int kk = 0; kk < 16; kk++) {
    float4 a = up4(row[kk]);
    float4 b0 = ld4(Wf + (kk * 4 + 0) * 64 + j4);
    float4 b1 = ld4(Wf + (kk * 4 + 1) * 64 + j4);
    float4 b2 = ld4(Wf + (kk * 4 + 2) * 64 + j4);
    float4 b3 = ld4(Wf + (kk * 4 + 3) * 64 + j4);
    ax = fmaf(a.x, b0.x, ax); ay = fmaf(a.x, b0.y, ay); az = fmaf(a.x, b0.z, az); aw = fmaf(a.x, b0.w, aw);
    ax = fmaf(a.y, b1.x, ax); ay = fmaf(a.y, b1.y, ay); az = fmaf(a.y, b1.z, az); aw = fmaf(a.y, b1.w, aw);
    ax = fmaf(a.z, b2.x, ax); ay = fmaf(a.z, b2.y, ay); az = fmaf(a.z, b2.z, az); aw = fmaf(a.z, b2.w, aw);
    ax = fmaf(a.w, b3.x, ax); ay = fmaf(a.w, b3.y, ay); az = fmaf(a.w, b3.z, az); aw = fmaf(a.w, b3.w, aw);
  }
  float4 bb = ld4(bf_ + j4);
  *(float4*)(out + (long)m * 64 + j4) = make_float4(ax + bb.x, ay + bb.y, az + bb.z, aw + bb.w);
}

extern "C" void kernel_launch(void* const* d_in, const int* in_sizes, int n_in,
                              void* d_out, int out_size, void* d_ws, size_t ws_size,
                              hipStream_t stream) {
  const float* x      = (const float*)d_in[0];
  const float* efeat  = (const float*)d_in[1];
  const int*   src    = (const int*)d_in[2];
  const int*   dst    = (const int*)d_in[3];
  const float* Wn0    = (const float*)d_in[4];
  const float* bn0    = (const float*)d_in[5];
  const float* We0    = (const float*)d_in[6];
  const float* be0    = (const float*)d_in[7];
  const float* Wnode  = (const float*)d_in[8];
  const float* bnode  = (const float*)d_in[9];
  const float* Wni    = (const float*)d_in[10];
  const float* Wnj    = (const float*)d_in[11];
  const float* Wfij   = (const float*)d_in[12];
  const float* attn   = (const float*)d_in[13];
  const float* bias_e = (const float*)d_in[14];
  const float* Wf     = (const float*)d_in[15];
  const float* bf     = (const float*)d_in[16];
  float* out = (float*)d_out;

  char* w = (char*)d_ws;
  auto alloc = [&](size_t nbytes) { char* p = w; w += (nbytes + 255) & ~(size_t)255; return p; };
  uint2* h_a   = (uint2*)alloc((size_t)NN * 128);    // bf16 [NN][64]
  uint2* h_b   = (uint2*)alloc((size_t)NN * 128);
  uint2* f_a   = (uint2*)alloc((size_t)NE * 128);    // bf16 [NE][64], CSR edge order
  uint2* f_b   = (uint2*)alloc((size_t)NE * 128);
  float* scc   = (float*)alloc((size_t)NE * 16);     // scores, CSR order [E][4]
  uint*  Wcat  = (uint*)alloc((size_t)2 * 24576 * 4);
  uint*  WcT   = (uint*)alloc((size_t)2 * 8192 * 4);
  float* bmean = (float*)alloc((size_t)2 * 64 * 4);
  int* deg     = (int*)alloc((size_t)NN * 2 * 4);
  int* cursor  = deg + NN;
  int* off     = (int*)alloc((size_t)(NN + 1) * 4);
  int* esrc    = (int*)alloc((size_t)NE * 4);
  int* edst    = (int*)alloc((size_t)NE * 4);
  int* csr_pos = (int*)alloc((size_t)NE * 4);
  int* bsum    = (int*)alloc((size_t)128 * 4);

  zero_i32<<<(2 * NN + 255) / 256, 256, 0, stream>>>(deg, 2 * NN);
  count_deg<<<(NE + 255) / 256, 256, 0, stream>>>(dst, deg);
  scan1<<<SCAN_BLOCKS, 256, 0, stream>>>(deg, off, bsum);
  scan2<<<1, 128, 0, stream>>>(bsum, off);
  scan3<<<SCAN_BLOCKS, 256, 0, stream>>>(off, bsum);
  fill_csr<<<(NE + 255) / 256, 256, 0, stream>>>(dst, src, off, cursor, esrc, edst, csr_pos);

  gemm16_bf16<<<(NN * 4 + 255) / 256, 256, 0, stream>>>(x, Wn0, bn0, h_a, NN, 65, nullptr);
  gemm16_bf16<<<(NE * 4 + 255) / 256, 256, 0, stream>>>(efeat, We0, be0, f_a, NE, 15, csr_pos);
  prep_w<<<4, 256, 0, stream>>>(Wni, Wnj, Wfij, Wnode, bnode, Wcat, WcT, bmean);

  uint2* hc = h_a; uint2* hn = h_b;
  uint2* fc = f_a; uint2* fn = f_b;
  for (int l = 0; l < 2; l++) {
    const uint* Wcat_l = Wcat + (size_t)l * 24576;
    const uint4* WcT_l = (const uint4*)(WcT + (size_t)l * 8192);
    const float* bm_l  = bmean + (size_t)l * 64;
    const float* be_l  = bias_e + (size_t)l * 256;
    const float* at_l  = attn + (size_t)l * 256;
    edge_mfma<<<GRID_E, 256, 0, stream>>>((const uint4*)fc, (const uint4*)hc,
                                          Wcat_l, be_l, at_l, esrc, edst, scc,
                                          (uint4*)fn);
    agg_combine<<<NN / 16, 256, 0, stream>>>((const uint2*)hc, (const float4*)scc,
                                             esrc, off, WcT_l, bm_l, (uint4*)hn);
    uint2* tmp = hc; hc = hn; hn = tmp;
    tmp = fc; fc = fn; fn = tmp;
  }
  final_gemm<<<(NN * 16 + 255) / 256, 256, 0, stream>>>(hc, Wf, bf, out);
}